// Round 1
// baseline (212.086 us; speedup 1.0000x reference)
//
#include <hip/hip_runtime.h>

// WaveletTransform: Haar 2x2 on (8, 64, 512, 512) fp32 -> 4x (8, 64, 256, 256) fp32
// Memory-bound single pass: float4 loads (2 input rows), float2 stores x4 subbands.

#define BB 8
#define CC 64
#define HH_ 512
#define WW_ 512
#define OUTH (HH_ / 2)
#define OUTW (WW_ / 2)

__global__ __launch_bounds__(256) void haar2x2_kernel(
    const float* __restrict__ x, float* __restrict__ out, int total)
{
    // one work item = one float4 span of an input row-pair = 2 output pixels
    // per-image work: OUTH row-pairs * (WW_/4) quads = 256 * 128 = 32768
    const size_t subband = (size_t)BB * CC * OUTH * OUTW;  // 33554432

    int idx = blockIdx.x * blockDim.x + threadIdx.x;
    int stride = gridDim.x * blockDim.x;

    for (int t = idx; t < total; t += stride) {
        int img = t >> 15;        // / 32768
        int rem = t & 32767;
        int ho  = rem >> 7;       // output row, 0..255
        int wq  = rem & 127;      // float4 quad index within the input row

        const float* rowbase = x + (size_t)img * HH_ * WW_ + (size_t)(2 * ho) * WW_;
        float4 r0 = *(reinterpret_cast<const float4*>(rowbase) + wq);          // a0 b0 a1 b1
        float4 r1 = *(reinterpret_cast<const float4*>(rowbase + WW_) + wq);    // c0 d0 c1 d1

        // pixel 0: a=r0.x b=r0.y c=r1.x d=r1.y
        float s0 = r0.x + r0.y, d0 = r0.x - r0.y;
        float s1 = r1.x + r1.y, d1 = r1.x - r1.y;
        float ll0 = (s0 + s1) * 0.5f;
        float lh0 = (s0 - s1) * 0.5f;
        float hl0 = (d0 + d1) * 0.5f;
        float hh0 = (d0 - d1) * 0.5f;

        // pixel 1: a=r0.z b=r0.w c=r1.z d=r1.w
        float s2 = r0.z + r0.w, d2 = r0.z - r0.w;
        float s3 = r1.z + r1.w, d3 = r1.z - r1.w;
        float ll1 = (s2 + s3) * 0.5f;
        float lh1 = (s2 - s3) * 0.5f;
        float hl1 = (d2 + d3) * 0.5f;
        float hh1 = (d2 - d3) * 0.5f;

        size_t obase = (size_t)img * OUTH * OUTW + (size_t)ho * OUTW + (size_t)(wq * 2);
        *reinterpret_cast<float2*>(out + 0 * subband + obase) = make_float2(ll0, ll1);
        *reinterpret_cast<float2*>(out + 1 * subband + obase) = make_float2(lh0, lh1);
        *reinterpret_cast<float2*>(out + 2 * subband + obase) = make_float2(hl0, hl1);
        *reinterpret_cast<float2*>(out + 3 * subband + obase) = make_float2(hh0, hh1);
    }
}

extern "C" void kernel_launch(void* const* d_in, const int* in_sizes, int n_in,
                              void* d_out, int out_size, void* d_ws, size_t ws_size,
                              hipStream_t stream) {
    const float* x = (const float*)d_in[0];
    float* out = (float*)d_out;

    const int total = BB * CC * OUTH * (WW_ / 4);  // 16,777,216 work items
    const int block = 256;
    const int grid = 2048;                          // grid-stride, memory-bound default

    haar2x2_kernel<<<grid, block, 0, stream>>>(x, out, total);
}

// Round 3
// 198.988 us; speedup vs baseline: 1.0658x; 1.0658x over previous
//
#include <hip/hip_runtime.h>

// WaveletTransform: Haar 2x2 on (8, 64, 512, 512) fp32 -> 4x (8, 64, 256, 256) fp32
// Memory-bound single pass. Per thread: 8 input cols x 2 rows (4x 16B loads)
// -> 4 output pixels per subband (4x 16B nontemporal stores).

#define BB 8
#define CC 64
#define HH_ 512
#define WW_ 512
#define OUTH (HH_ / 2)
#define OUTW (WW_ / 2)

typedef float v4f __attribute__((ext_vector_type(4)));

__global__ __launch_bounds__(256) void haar2x2_kernel(
    const float* __restrict__ x, float* __restrict__ out, int total)
{
    // per-image work: OUTH row-pairs * (WW_/8) octs = 256 * 64 = 16384 = 2^14
    const size_t subband = (size_t)BB * CC * OUTH * OUTW;  // 33554432

    int idx = blockIdx.x * blockDim.x + threadIdx.x;
    int stride = gridDim.x * blockDim.x;

    for (int t = idx; t < total; t += stride) {
        int img = t >> 14;
        int rem = t & 16383;
        int ho  = rem >> 6;       // output row, 0..255
        int wo  = rem & 63;       // 8-column group index within the input row

        const float* rowbase = x + (size_t)img * HH_ * WW_ + (size_t)(2 * ho) * WW_;
        const v4f* r0p = reinterpret_cast<const v4f*>(rowbase) + wo * 2;
        const v4f* r1p = reinterpret_cast<const v4f*>(rowbase + WW_) + wo * 2;

        v4f r0a = __builtin_nontemporal_load(r0p);      // a0 b0 a1 b1
        v4f r0b = __builtin_nontemporal_load(r0p + 1);  // a2 b2 a3 b3
        v4f r1a = __builtin_nontemporal_load(r1p);      // c0 d0 c1 d1
        v4f r1b = __builtin_nontemporal_load(r1p + 1);  // c2 d2 c3 d3

        v4f ll, lh, hl, hh;

        // pixel 0: a=r0a.x b=r0a.y c=r1a.x d=r1a.y
        {
            float s0 = r0a.x + r0a.y, d0 = r0a.x - r0a.y;
            float s1 = r1a.x + r1a.y, d1 = r1a.x - r1a.y;
            ll.x = (s0 + s1) * 0.5f; lh.x = (s0 - s1) * 0.5f;
            hl.x = (d0 + d1) * 0.5f; hh.x = (d0 - d1) * 0.5f;
        }
        // pixel 1
        {
            float s0 = r0a.z + r0a.w, d0 = r0a.z - r0a.w;
            float s1 = r1a.z + r1a.w, d1 = r1a.z - r1a.w;
            ll.y = (s0 + s1) * 0.5f; lh.y = (s0 - s1) * 0.5f;
            hl.y = (d0 + d1) * 0.5f; hh.y = (d0 - d1) * 0.5f;
        }
        // pixel 2
        {
            float s0 = r0b.x + r0b.y, d0 = r0b.x - r0b.y;
            float s1 = r1b.x + r1b.y, d1 = r1b.x - r1b.y;
            ll.z = (s0 + s1) * 0.5f; lh.z = (s0 - s1) * 0.5f;
            hl.z = (d0 + d1) * 0.5f; hh.z = (d0 - d1) * 0.5f;
        }
        // pixel 3
        {
            float s0 = r0b.z + r0b.w, d0 = r0b.z - r0b.w;
            float s1 = r1b.z + r1b.w, d1 = r1b.z - r1b.w;
            ll.w = (s0 + s1) * 0.5f; lh.w = (s0 - s1) * 0.5f;
            hl.w = (d0 + d1) * 0.5f; hh.w = (d0 - d1) * 0.5f;
        }

        size_t obase = (size_t)img * OUTH * OUTW + (size_t)ho * OUTW + (size_t)(wo * 4);
        __builtin_nontemporal_store(ll, reinterpret_cast<v4f*>(out + 0 * subband + obase));
        __builtin_nontemporal_store(lh, reinterpret_cast<v4f*>(out + 1 * subband + obase));
        __builtin_nontemporal_store(hl, reinterpret_cast<v4f*>(out + 2 * subband + obase));
        __builtin_nontemporal_store(hh, reinterpret_cast<v4f*>(out + 3 * subband + obase));
    }
}

extern "C" void kernel_launch(void* const* d_in, const int* in_sizes, int n_in,
                              void* d_out, int out_size, void* d_ws, size_t ws_size,
                              hipStream_t stream) {
    const float* x = (const float*)d_in[0];
    float* out = (float*)d_out;

    const int total = BB * CC * OUTH * (WW_ / 8);  // 8,388,608 work items
    const int block = 256;
    const int grid = 2048;                          // grid-stride, memory-bound default

    haar2x2_kernel<<<grid, block, 0, stream>>>(x, out, total);
}